// Round 1
// baseline (175.433 us; speedup 1.0000x reference)
//
#include <hip/hip_runtime.h>
#include <hip/hip_bf16.h>

#define DIN  256
#define DOUT 256
#define KNEI 16

typedef __attribute__((ext_vector_type(4))) float f32x4;
typedef __attribute__((ext_vector_type(8))) short bf16x8;
typedef __attribute__((ext_vector_type(4))) short bf16x4;

__device__ __forceinline__ short f2bf(float f) {
    unsigned int u;
    __builtin_memcpy(&u, &f, 4);
    unsigned int r = (u + 0x7fffu + ((u >> 16) & 1u)) >> 16;
    return (short)r;
}

__device__ __forceinline__ float bf2f(short s) {
    unsigned int u = ((unsigned int)(unsigned short)s) << 16;
    float f;
    __builtin_memcpy(&f, &u, 4);
    return f;
}

// ---------------------------------------------------------------------------
// K0: pack W (f32 [DOUT][DIN]) into bf16 MFMA B-fragment layout.
// Fragment (cb, kb): cb = 16-col block (0..15), kb = 32-k block (0..7).
// Lane l of fragment holds B[k = kb*32 + (l>>4)*8 + j][col = cb*16 + (l&15)]
//   = W[col][k], j = 0..7 (16 contiguous bytes along DIN).
// Storage: Wp + ((cb*8 + kb)*64 + lane)*8 bf16  -> perfectly coalesced loads.
// ---------------------------------------------------------------------------
__global__ __launch_bounds__(256) void pack_w_kernel(
        const float* __restrict__ W, short* __restrict__ Wp) {
    int gid  = blockIdx.x * 256 + threadIdx.x;   // 8192 threads total
    int lane = gid & 63;
    int frag = gid >> 6;                         // 0..127
    int kb   = frag & 7;
    int cb   = frag >> 3;
    int col  = cb * 16 + (lane & 15);
    int k0   = kb * 32 + (lane >> 4) * 8;
    const float* src = W + (size_t)col * DIN + k0;
    bf16x8 v;
#pragma unroll
    for (int j = 0; j < 8; ++j) v[j] = f2bf(src[j]);
    *((bf16x8*)Wp + (size_t)frag * 64 + lane) = v;
}

// ---------------------------------------------------------------------------
// K1: supports = wv @ W^T + b   (bf16 MFMA, f32 accumulate)
// 64 rows per block, full N=256 cols, full K=256 staged once in swizzled LDS.
// 4 waves: wave w owns cols [w*64, w*64+64). acc[4][4] 16x16 fragments.
// Also writes bf16 shadow copy for the gather kernel.
// ---------------------------------------------------------------------------
__global__ __launch_bounds__(256) void gemm_kernel(
        const float* __restrict__ A, const short* __restrict__ Wp,
        const float* __restrict__ bias, float* __restrict__ out,
        short* __restrict__ out_bf, int M, int write_bf) {
    __shared__ short lds[64 * 256];              // 32 KB, XOR-swizzled
    const int tid  = threadIdx.x;
    const int row0 = blockIdx.x * 64;

    // ---- stage A tile (64 x 256 f32 -> bf16), one pass, one barrier ----
#pragma unroll
    for (int it = 0; it < 16; ++it) {
        int r   = it * 4 + (tid >> 6);           // 0..63
        int c4  = (tid & 63) * 4;                // f32 col 0..252
        int row = row0 + r;
        f32x4 v = {0.f, 0.f, 0.f, 0.f};
        if (row < M) v = *(const f32x4*)(A + (size_t)row * DIN + c4);
        bf16x4 h;
#pragma unroll
        for (int j = 0; j < 4; ++j) h[j] = f2bf(v[j]);
        int byteoff = (r * 512 + c4 * 2) ^ ((r & 7) << 4);
        *(bf16x4*)((char*)lds + byteoff) = h;
    }
    __syncthreads();

    const int wid  = tid >> 6;
    const int lane = tid & 63;
    f32x4 acc[4][4];
#pragma unroll
    for (int i = 0; i < 4; ++i)
#pragma unroll
        for (int j = 0; j < 4; ++j) acc[i][j] = f32x4{0.f, 0.f, 0.f, 0.f};

    const bf16x8* wp = (const bf16x8*)Wp;
#pragma unroll
    for (int kb = 0; kb < 8; ++kb) {
        bf16x8 a[4], b[4];
#pragma unroll
        for (int i = 0; i < 4; ++i) {
            int r       = i * 16 + (lane & 15);
            int cbyte   = kb * 64 + (lane >> 4) * 16;
            int byteoff = (r * 512 + cbyte) ^ ((r & 7) << 4);
            a[i] = *(const bf16x8*)((const char*)lds + byteoff);
        }
#pragma unroll
        for (int j = 0; j < 4; ++j) {
            int cb = wid * 4 + j;
            b[j] = wp[(size_t)(cb * 8 + kb) * 64 + lane];
        }
#pragma unroll
        for (int i = 0; i < 4; ++i)
#pragma unroll
            for (int j = 0; j < 4; ++j)
                acc[i][j] = __builtin_amdgcn_mfma_f32_16x16x32_bf16(
                    a[i], b[j], acc[i][j], 0, 0, 0);
    }

    // ---- epilogue: C[row][col], col = lane&15, row = (lane>>4)*4 + reg ----
#pragma unroll
    for (int i = 0; i < 4; ++i) {
#pragma unroll
        for (int j = 0; j < 4; ++j) {
            int   col = wid * 64 + j * 16 + (lane & 15);
            float bv  = bias[col];
#pragma unroll
            for (int reg = 0; reg < 4; ++reg) {
                int row = row0 + i * 16 + (lane >> 4) * 4 + reg;
                if (row < M) {
                    float v = acc[i][j][reg] + bv;
                    out[(size_t)row * DOUT + col] = v;
                    if (write_bf)
                        out_bf[(size_t)row * DOUT + col] = f2bf(v);
                }
            }
        }
    }
}

// ---------------------------------------------------------------------------
// K2: per source row s (one wave each):
//   res = src + leaky(sum_k mask[s,k]*supports[neigh[s,k]] + src)
// Gathers from bf16 shadow (or f32 supports as fallback); writes ws rows.
// ---------------------------------------------------------------------------
__global__ __launch_bounds__(256) void aggregate_kernel(
        const float* __restrict__ supports, const short* __restrict__ sup_bf,
        const int* __restrict__ src_idx, const int* __restrict__ neighs,
        const float* __restrict__ mask, float* __restrict__ outrows,
        int S, int use_bf) {
    int s = __builtin_amdgcn_readfirstlane(blockIdx.x * 4 + (threadIdx.x >> 6));
    if (s >= S) return;
    const int lane = threadIdx.x & 63;
    const int c4   = lane * 4;

    f32x4 acc = {0.f, 0.f, 0.f, 0.f};
    if (use_bf) {
#pragma unroll
        for (int k = 0; k < KNEI; ++k) {
            int   idx = neighs[(size_t)s * KNEI + k];
            float m   = mask[(size_t)s * KNEI + k];
            bf16x4 v = *(const bf16x4*)(sup_bf + (size_t)idx * DOUT + c4);
#pragma unroll
            for (int j = 0; j < 4; ++j) acc[j] += m * bf2f(v[j]);
        }
    } else {
#pragma unroll
        for (int k = 0; k < KNEI; ++k) {
            int   idx = neighs[(size_t)s * KNEI + k];
            float m   = mask[(size_t)s * KNEI + k];
            f32x4 v = *(const f32x4*)(supports + (size_t)idx * DOUT + c4);
#pragma unroll
            for (int j = 0; j < 4; ++j) acc[j] += m * v[j];
        }
    }

    int srow = src_idx[s];
    f32x4 sv = *(const f32x4*)(supports + (size_t)srow * DOUT + c4);
    f32x4 res;
#pragma unroll
    for (int j = 0; j < 4; ++j) {
        float o = acc[j] + sv[j];
        o = (o >= 0.f) ? o : 0.2f * o;
        res[j] = sv[j] + o;
    }
    *(f32x4*)(outrows + (size_t)s * DOUT + c4) = res;
}

// ---------------------------------------------------------------------------
// K3: scatter updated rows back: out[src_idx[s]] = outrows[s]
// ---------------------------------------------------------------------------
__global__ __launch_bounds__(256) void scatter_kernel(
        const float* __restrict__ outrows, const int* __restrict__ src_idx,
        float* __restrict__ out, int S) {
    int gid = blockIdx.x * 256 + threadIdx.x;
    int s   = gid >> 6;
    if (s >= S) return;
    int lane = gid & 63;
    int row  = src_idx[s];
    *(f32x4*)(out + (size_t)row * DOUT + lane * 4) =
        *(const f32x4*)(outrows + (size_t)s * DOUT + lane * 4);
}

extern "C" void kernel_launch(void* const* d_in, const int* in_sizes, int n_in,
                              void* d_out, int out_size, void* d_ws, size_t ws_size,
                              hipStream_t stream) {
    (void)n_in; (void)out_size;
    const float* wv     = (const float*)d_in[0];
    const int*   src_i  = (const int*)d_in[1];
    const int*   neighs = (const int*)d_in[2];
    const float* mask   = (const float*)d_in[3];
    const float* W      = (const float*)d_in[4];
    const float* bias   = (const float*)d_in[5];
    float* out = (float*)d_out;

    const int N = in_sizes[0] / DIN;   // 100000
    const int S = in_sizes[1];         // 50000

    // workspace layout: [outrows f32 S*256][Wp bf16 256*256][sup_bf bf16 N*256]
    char*  ws       = (char*)d_ws;
    size_t sz_rows  = (size_t)S * DOUT * 4;
    size_t off_wp   = (sz_rows + 1023) & ~(size_t)1023;
    size_t sz_wp    = (size_t)DOUT * DIN * 2;
    size_t off_bf   = off_wp + sz_wp;
    size_t need_bf  = off_bf + (size_t)N * DOUT * 2;

    float* outrows = (float*)ws;
    short* Wp      = (short*)(ws + off_wp);
    short* sup_bf  = (short*)(ws + off_bf);
    int use_bf = (ws_size >= need_bf) ? 1 : 0;

    pack_w_kernel<<<32, 256, 0, stream>>>(W, Wp);

    int mblocks = (N + 63) / 64;
    gemm_kernel<<<mblocks, 256, 0, stream>>>(wv, Wp, bias, out, sup_bf, N, use_bf);

    aggregate_kernel<<<(S + 3) / 4, 256, 0, stream>>>(
        out, sup_bf, src_i, neighs, mask, outrows, S, use_bf);

    scatter_kernel<<<((size_t)S * 64 + 255) / 256, 256, 0, stream>>>(
        outrows, src_i, out, S);
}

// Round 2
// 144.583 us; speedup vs baseline: 1.2134x; 1.2134x over previous
//
#include <hip/hip_runtime.h>
#include <hip/hip_bf16.h>

#define DIN  256
#define DOUT 256
#define KNEI 16

typedef __attribute__((ext_vector_type(4))) float f32x4;
typedef __attribute__((ext_vector_type(8))) short bf16x8;
typedef __attribute__((ext_vector_type(4))) short bf16x4;

__device__ __forceinline__ short f2bf(float f) {
    unsigned int u;
    __builtin_memcpy(&u, &f, 4);
    unsigned int r = (u + 0x7fffu + ((u >> 16) & 1u)) >> 16;
    return (short)r;
}

__device__ __forceinline__ float bf2f(short s) {
    unsigned int u = ((unsigned int)(unsigned short)s) << 16;
    float f;
    __builtin_memcpy(&f, &u, 4);
    return f;
}

// ---------------------------------------------------------------------------
// K0: pack W (f32 [DOUT][DIN]) into bf16 MFMA fragment layout.
// Fragment (cb, kb): lane l holds W[col = cb*16 + (l&15)][k = kb*32 + (l>>4)*8 + j]
// Stored at Wp + ((cb*8 + kb)*64 + lane)*8 bf16 -> coalesced fragment loads.
// Used as the MFMA *A* operand (m = dout index at l&15).
// ---------------------------------------------------------------------------
__global__ __launch_bounds__(256) void pack_w_kernel(
        const float* __restrict__ W, short* __restrict__ Wp) {
    int gid  = blockIdx.x * 256 + threadIdx.x;   // 8192 threads total
    int lane = gid & 63;
    int frag = gid >> 6;                         // 0..127
    int kb   = frag & 7;
    int cb   = frag >> 3;
    int col  = cb * 16 + (lane & 15);
    int k0   = kb * 32 + (lane >> 4) * 8;
    const float* src = W + (size_t)col * DIN + k0;
    bf16x8 v;
#pragma unroll
    for (int j = 0; j < 8; ++j) v[j] = f2bf(src[j]);
    *((bf16x8*)Wp + (size_t)frag * 64 + lane) = v;
}

// ---------------------------------------------------------------------------
// K1: supports = wv @ W^T + b   (bf16 MFMA, f32 accumulate)
// No LDS, no barriers. Each wave owns 16 rows; loads its entire 16x256 f32
// A-slab into registers up front (16 loads in flight -> latency pipelined),
// converts once to bf16 fragments, then 8x16 MFMA vs L2-resident Wp.
// Swapped operands: D[m=dout][n=row] -> lane holds 4 consecutive douts of one
// row => f32x4 / bf16x4 wide stores.
// ---------------------------------------------------------------------------
__global__ __launch_bounds__(256) void gemm_kernel(
        const float* __restrict__ A, const short* __restrict__ Wp,
        const float* __restrict__ bias, float* __restrict__ out,
        short* __restrict__ out_bf, int M) {
    const int tid  = threadIdx.x;
    const int wid  = tid >> 6;
    const int lane = tid & 63;
    const int row0 = (blockIdx.x * 4 + wid) * 16;
    if (row0 >= M) return;

    const int r = row0 + (lane & 15);
    const int g = lane >> 4;

    // ---- load the wave's A slab: per lane 64 floats (16x f32x4) ----
    const float* arow = A + (size_t)r * DIN + g * 8;
    f32x4 araw[16];
#pragma unroll
    for (int kb = 0; kb < 8; ++kb) {
        araw[2 * kb]     = *(const f32x4*)(arow + kb * 32);
        araw[2 * kb + 1] = *(const f32x4*)(arow + kb * 32 + 4);
    }
    bf16x8 afrag[8];
#pragma unroll
    for (int kb = 0; kb < 8; ++kb) {
#pragma unroll
        for (int j = 0; j < 4; ++j) {
            afrag[kb][j]     = f2bf(araw[2 * kb][j]);
            afrag[kb][4 + j] = f2bf(araw[2 * kb + 1][j]);
        }
    }

    f32x4 acc[16];
#pragma unroll
    for (int cb = 0; cb < 16; ++cb) acc[cb] = f32x4{0.f, 0.f, 0.f, 0.f};

    const bf16x8* wp = (const bf16x8*)Wp;
#pragma unroll
    for (int kb = 0; kb < 8; ++kb) {
#pragma unroll
        for (int cb = 0; cb < 16; ++cb) {
            bf16x8 w = wp[(size_t)(cb * 8 + kb) * 64 + lane];
            acc[cb] = __builtin_amdgcn_mfma_f32_16x16x32_bf16(
                w, afrag[kb], acc[cb], 0, 0, 0);
        }
    }

    // ---- epilogue: D layout m=dout=(g*4+reg) within cb*16, n=row=lane&15 ----
    float* orow = out    + (size_t)r * DOUT;
    short* brow = out_bf + (size_t)r * DOUT;
#pragma unroll
    for (int cb = 0; cb < 16; ++cb) {
        int c0 = cb * 16 + g * 4;
        f32x4 bv = *(const f32x4*)(bias + c0);
        f32x4 v  = acc[cb] + bv;
        __builtin_nontemporal_store(v, (f32x4*)(orow + c0));  // never re-read
        bf16x4 h;
#pragma unroll
        for (int j = 0; j < 4; ++j) h[j] = f2bf(v[j]);
        *(bf16x4*)(brow + c0) = h;                            // re-read 16x: cache
    }
}

// ---------------------------------------------------------------------------
// K2 (fused): per source row s (one wave):
//   sv  = sup_bf[src_idx[s]]              (immutable bf16 shadow)
//   agg = sum_k mask[s,k] * sup_bf[neigh[s,k]]
//   out[src_idx[s]] = sv + leaky(agg + sv)
// Writes directly to out: race-free since src_idx unique and all gathers hit
// the shadow, never out.
// ---------------------------------------------------------------------------
__global__ __launch_bounds__(256) void aggregate_fused_kernel(
        const short* __restrict__ sup_bf, const int* __restrict__ src_idx,
        const int* __restrict__ neighs, const float* __restrict__ mask,
        float* __restrict__ out, int S) {
    int s = blockIdx.x * 4 + (threadIdx.x >> 6);
    if (s >= S) return;
    s = __builtin_amdgcn_readfirstlane(s);
    const int lane = threadIdx.x & 63;
    const int c4   = lane * 4;

    f32x4 acc = {0.f, 0.f, 0.f, 0.f};
#pragma unroll
    for (int k = 0; k < KNEI; ++k) {
        int   idx = neighs[(size_t)s * KNEI + k];
        float m   = mask[(size_t)s * KNEI + k];
        bf16x4 v = *(const bf16x4*)(sup_bf + (size_t)idx * DOUT + c4);
#pragma unroll
        for (int j = 0; j < 4; ++j) acc[j] += m * bf2f(v[j]);
    }

    int srow = src_idx[s];
    bf16x4 svh = *(const bf16x4*)(sup_bf + (size_t)srow * DOUT + c4);
    f32x4 res;
#pragma unroll
    for (int j = 0; j < 4; ++j) {
        float sv = bf2f(svh[j]);
        float o  = acc[j] + sv;
        o = (o >= 0.f) ? o : 0.2f * o;
        res[j] = sv + o;
    }
    __builtin_nontemporal_store(res, (f32x4*)(out + (size_t)srow * DOUT + c4));
}

// ---------------------------------------------------------------------------
// Fallback path (ws too small for bf16 shadow): aggregate from f32 out into
// ws rows, then scatter back. (Two kernels to keep pre-update reads safe.)
// ---------------------------------------------------------------------------
__global__ __launch_bounds__(256) void aggregate_f32_kernel(
        const float* __restrict__ supports, const int* __restrict__ src_idx,
        const int* __restrict__ neighs, const float* __restrict__ mask,
        float* __restrict__ outrows, int S) {
    int s = blockIdx.x * 4 + (threadIdx.x >> 6);
    if (s >= S) return;
    s = __builtin_amdgcn_readfirstlane(s);
    const int lane = threadIdx.x & 63;
    const int c4   = lane * 4;
    f32x4 acc = {0.f, 0.f, 0.f, 0.f};
#pragma unroll
    for (int k = 0; k < KNEI; ++k) {
        int   idx = neighs[(size_t)s * KNEI + k];
        float m   = mask[(size_t)s * KNEI + k];
        f32x4 v = *(const f32x4*)(supports + (size_t)idx * DOUT + c4);
#pragma unroll
        for (int j = 0; j < 4; ++j) acc[j] += m * v[j];
    }
    int srow = src_idx[s];
    f32x4 sv = *(const f32x4*)(supports + (size_t)srow * DOUT + c4);
    f32x4 res;
#pragma unroll
    for (int j = 0; j < 4; ++j) {
        float o = acc[j] + sv[j];
        o = (o >= 0.f) ? o : 0.2f * o;
        res[j] = sv[j] + o;
    }
    *(f32x4*)(outrows + (size_t)s * DOUT + c4) = res;
}

__global__ __launch_bounds__(256) void scatter_kernel(
        const float* __restrict__ outrows, const int* __restrict__ src_idx,
        float* __restrict__ out, int S) {
    int gid = blockIdx.x * 256 + threadIdx.x;
    int s   = gid >> 6;
    if (s >= S) return;
    int lane = gid & 63;
    int row  = src_idx[s];
    *(f32x4*)(out + (size_t)row * DOUT + lane * 4) =
        *(const f32x4*)(outrows + (size_t)s * DOUT + lane * 4);
}

extern "C" void kernel_launch(void* const* d_in, const int* in_sizes, int n_in,
                              void* d_out, int out_size, void* d_ws, size_t ws_size,
                              hipStream_t stream) {
    (void)n_in; (void)out_size;
    const float* wv     = (const float*)d_in[0];
    const int*   src_i  = (const int*)d_in[1];
    const int*   neighs = (const int*)d_in[2];
    const float* mask   = (const float*)d_in[3];
    const float* W      = (const float*)d_in[4];
    const float* bias   = (const float*)d_in[5];
    float* out = (float*)d_out;

    const int N = in_sizes[0] / DIN;   // 100000
    const int S = in_sizes[1];         // 50000

    // workspace: [Wp bf16 256*256][sup_bf bf16 N*256]  (fused path)
    //            [Wp bf16 256*256][outrows f32 S*256]  (fallback path)
    char*  ws      = (char*)d_ws;
    size_t sz_wp   = (size_t)DOUT * DIN * 2;
    size_t off_buf = (sz_wp + 1023) & ~(size_t)1023;
    short* Wp      = (short*)ws;
    short* sup_bf  = (short*)(ws + off_buf);
    float* outrows = (float*)(ws + off_buf);
    int fused = (ws_size >= off_buf + (size_t)N * DOUT * 2) ? 1 : 0;

    pack_w_kernel<<<32, 256, 0, stream>>>(W, Wp);

    int mwaves  = (N + 15) / 16;
    int mblocks = (mwaves + 3) / 4;
    gemm_kernel<<<mblocks, 256, 0, stream>>>(wv, Wp, bias, out, sup_bf, N);

    if (fused) {
        aggregate_fused_kernel<<<(S + 3) / 4, 256, 0, stream>>>(
            sup_bf, src_i, neighs, mask, out, S);
    } else {
        aggregate_f32_kernel<<<(S + 3) / 4, 256, 0, stream>>>(
            out, src_i, neighs, mask, outrows, S);
        scatter_kernel<<<((size_t)S * 64 + 255) / 256, 256, 0, stream>>>(
            outrows, src_i, out, S);
    }
}